// Round 17
// baseline (449.792 us; speedup 1.0000x reference)
//
#include <hip/hip_runtime.h>

typedef unsigned short u16;
typedef unsigned int u32;
typedef unsigned long long u64;
typedef short bf16x8 __attribute__((ext_vector_type(8)));
typedef float f32x4 __attribute__((ext_vector_type(4)));
typedef u32 u32x4 __attribute__((ext_vector_type(4)));

__device__ __forceinline__ float b2f(u16 u) {
    return __uint_as_float(((u32)u) << 16);
}
__device__ __forceinline__ u16 f2b(float f) {  // RNE
    u32 u = __float_as_uint(f);
    u32 r = u + 0x7fffu + ((u >> 16) & 1u);
    return (u16)(r >> 16);
}
__device__ __forceinline__ f32x4 mfma16(bf16x8 a, bf16x8 b, f32x4 c) {
    return __builtin_amdgcn_mfma_f32_16x16x32_bf16(a, b, c, 0, 0, 0);
}

// ---------------------------------------------------------------------------
// prep: weights. seg -> W^T[n][k] row-major split bf16 (hi, lo planes).
// seg_bf -> MFMA B-fragment order: [tile][ks][lane][8]. seg_uv -> stacked
// [(Wa1-Wa2)^T ; Wa2^T].
// ---------------------------------------------------------------------------
template<int NP, int KP, int R, int C>
__device__ __forceinline__ bool seg(int t, int base, const float* src, u16* dst) {
    int r = t - base;
    if (r < 0) return true;
    constexpr int RNG = NP * KP;
    if (r >= RNG) return false;
    int n = r / KP, k = r - n * KP;
    float v = (k < R && n < C) ? src[k * C + n] : 0.f;
    u16 hi = f2b(v);
    dst[r] = hi;
    dst[RNG + r] = f2b(v - b2f(hi));
    return true;
}
template<int NP, int KP, int R, int C>
__device__ __forceinline__ bool seg_bf(int t, int base, const float* src, u16* dst) {
    int r = t - base;
    if (r < 0) return true;
    constexpr int RNG = NP * KP;
    if (r >= RNG) return false;
    constexpr int KC = KP / 32;
    int j = r & 7, s = r >> 3;
    int lanei = s & 63;
    int ks = (s >> 6) % KC, tile = (s >> 6) / KC;
    int n = tile * 16 + (lanei & 15);
    int k = ks * 32 + (lanei >> 4) * 8 + j;
    float v = (k < R && n < C) ? src[k * C + n] : 0.f;
    u16 hi = f2b(v);
    dst[r] = hi;
    dst[RNG + r] = f2b(v - b2f(hi));
    return true;
}
template<int CMID, int CIN, int KP>
__device__ __forceinline__ bool seg_uv(int t, int base, const float* wa, u16* dst) {
    int r = t - base;
    if (r < 0) return true;
    constexpr int RNG = 2 * CMID * KP;
    if (r >= RNG) return false;
    int n = r / KP, k = r - n * KP;
    float v = 0.f;
    if (k < CIN) {
        if (n < CMID) v = wa[k * CMID + n] - wa[(CIN + k) * CMID + n];
        else          v = wa[(CIN + k) * CMID + (n - CMID)];
    }
    u16 hi = f2b(v);
    dst[r] = hi;
    dst[RNG + r] = f2b(v - b2f(hi));
    return true;
}

__global__ __launch_bounds__(256) void prep_weights(
    const float* w1a, const float* w1b, const float* w2a, const float* w2b,
    const float* w3a, const float* w3b, const float* wf1, const float* wf2,
    const float* wf3,
    u16* t1uv, u16* t2uv, u16* t3uv, u16* t1b, u16* t2b, u16* t3b,
    u16* tf1, u16* tf2, u16* tf3)
{
    int t = blockIdx.x * 256 + threadIdx.x;
    if (seg_uv< 64,   3,  32>(t,      0, w1a, t1uv)) return;
    if (seg_uv< 64,  64,  64>(t,   4096, w2a, t2uv)) return;
    if (seg_uv<128, 128, 128>(t,  12288, w3a, t3uv)) return;
    if (seg_bf< 64,  64,  64,  64>(t,  45056, w1b, t1b)) return;
    if (seg_bf<128,  64,  64, 128>(t,  49152, w2b, t2b)) return;
    if (seg_bf<512, 128, 128, 512>(t,  57344, w3b, t3b)) return;
    if (seg<512, 704, 704, 512>(t, 122880, wf1, tf1)) return;
    if (seg<256, 512, 512, 256>(t, 483328, wf2, tf2)) return;
    if (seg< 16, 256, 256,  12>(t, 614400, wf3, tf3)) return;
}

// ---------------------------------------------------------------------------
// kNN: one WAVE per point. Key = (orderable(d2) << 11) | idx, exact in f64
// (43 bits). Two-phase exact selection (R10-proven):
//  Phase 1: T = 32nd-smallest of the 64 lane-minima (bitonic across lanes).
//  Phase 2: ballot-compact keys <= T into LDS (cap 256), exact ascending
//    min-above-last on 4 keys/lane. Gate -> fallback (identical output).
// ---------------------------------------------------------------------------
__global__ __launch_bounds__(256) void knn_kernel(const float* __restrict__ pos,
                                                  int* __restrict__ idxout)
{
    int tid = threadIdx.x, lane = tid & 63, wv = tid >> 6;
    int p = blockIdx.x * 4 + wv;
    int b = p >> 11, n = p & 2047;
    __shared__ double cand[4][256];
    const float* pb = pos + (size_t)b * 2048 * 3;
    float pn0 = pb[n * 3 + 0], pn1 = pb[n * 3 + 1], pn2 = pb[n * 3 + 2];
    float sqn = __fadd_rn(__fadd_rn(__fmul_rn(pn0, pn0), __fmul_rn(pn1, pn1)),
                          __fmul_rn(pn2, pn2));
    double kd[32];
#pragma unroll
    for (int j = 0; j < 32; ++j) {
        int m = lane + j * 64;
        float q0 = pb[m * 3 + 0], q1 = pb[m * 3 + 1], q2 = pb[m * 3 + 2];
        float sqm = __fadd_rn(__fadd_rn(__fmul_rn(q0, q0), __fmul_rn(q1, q1)),
                              __fmul_rn(q2, q2));
        float dot = __fadd_rn(__fadd_rn(__fmul_rn(pn0, q0), __fmul_rn(pn1, q1)),
                              __fmul_rn(pn2, q2));
        float d2 = __fadd_rn(__fsub_rn(sqn, __fmul_rn(2.0f, dot)), sqm);
        u32 u = __float_as_uint(d2);
        u = (u & 0x80000000u) ? ~u : (u | 0x80000000u);  // orderable
        kd[j] = (double)((((u64)u) << 11) | (u32)m);
    }

    // Phase 1: lane-minima, bitonic sort across 64 lanes, T = 32nd smallest.
    double lmin = kd[0];
#pragma unroll
    for (int j = 1; j < 32; ++j) lmin = fmin(lmin, kd[j]);
    double v = lmin;
#pragma unroll
    for (int k = 2; k <= 64; k <<= 1) {
#pragma unroll
        for (int j2 = k >> 1; j2 > 0; j2 >>= 1) {
            double o = __shfl_xor(v, j2);
            bool up = ((lane & k) == 0);
            bool low = ((lane & j2) == 0);
            double mn = fmin(v, o), mx = fmax(v, o);
            v = (up == low) ? mn : mx;
        }
    }
    double T = __shfl(v, 31);

    // Phase 2: pad + ballot-compact keys <= T into LDS.
#pragma unroll
    for (int s = 0; s < 4; ++s) cand[wv][lane + s * 64] = 1e300;
    int base = 0;
#pragma unroll
    for (int j = 0; j < 32; ++j) {
        bool pred = (kd[j] <= T);
        u64 bal = __ballot(pred);
        int prefix = (int)__popcll(bal & ((1ull << lane) - 1ull));
        int slot = base + prefix;
        if (pred && slot < 256) cand[wv][slot] = kd[j];
        base += (int)__popcll(bal);
    }

    if (base >= 32 && base <= 256) {
        double kc[4];
#pragma unroll
        for (int j = 0; j < 4; ++j) kc[j] = cand[wv][lane * 4 + j];
        double last = -1.0;
        for (int it = 0; it < 32; ++it) {
            double lm = 1e300;
#pragma unroll
            for (int j = 0; j < 4; ++j) {
                double t = kc[j];
                lm = fmin(lm, (t > last) ? t : 1e300);
            }
#pragma unroll
            for (int off = 32; off; off >>= 1)
                lm = fmin(lm, __shfl_xor(lm, off));
            if (lane == 0) idxout[(size_t)p * 32 + it] = (int)(((u64)lm) & 2047u);
            last = lm;
        }
    } else {
        // Fallback: exact full-register selection (R9 path).
        double last = -1.0;
        for (int it = 0; it < 32; ++it) {
            double lm0 = 1e300, lm1 = 1e300;
#pragma unroll
            for (int j = 0; j < 32; j += 2) {
                double t0 = kd[j], t1 = kd[j + 1];
                lm0 = fmin(lm0, (t0 > last) ? t0 : 1e300);
                lm1 = fmin(lm1, (t1 > last) ? t1 : 1e300);
            }
            double lm = fmin(lm0, lm1);
#pragma unroll
            for (int off = 32; off; off >>= 1)
                lm = fmin(lm, __shfl_xor(lm, off));
            if (lane == 0) idxout[(size_t)p * 32 + it] = (int)(((u64)lm) & 2047u);
            last = lm;
        }
    }
}

// ---------------------------------------------------------------------------
// UV GEMM: U[n][c] = x@(Wa1-Wa2)+ba  (f32, exact, read once per point);
//          V[n][c] = x@Wa2           (bf16, gathered 32x -> half traffic).
// A f32 -> split LDS, 3-term MFMA vs split weights (defines U/V precision).
// ---------------------------------------------------------------------------
template<int K, int KP, int N2>
__global__ __launch_bounds__(256) void uv_gemm(
    const float* __restrict__ xin, const u16* __restrict__ wT,
    const float* __restrict__ ba, float* __restrict__ Uf, u16* __restrict__ Vb)
{
    constexpr int SA = KP + 8;
    constexpr int WSZ = N2 * KP;
    constexpr int CMID = N2 / 2;
    __shared__ __align__(16) u16 AsH[32 * SA];
    __shared__ __align__(16) u16 AsL[32 * SA];
    int row0 = blockIdx.x * 32;
    int tid = threadIdx.x, lane = tid & 63, wv = tid >> 6, ln = lane & 15, q = lane >> 4;

    for (int e = tid; e < 32 * (KP / 8); e += 256) {
        int r = e / (KP / 8), c0 = (e % (KP / 8)) * 8;
        bf16x8 hv, lv;
#pragma unroll
        for (int jj = 0; jj < 8; ++jj) {
            int c = c0 + jj;
            float v = (c < K) ? xin[(size_t)(row0 + r) * K + c] : 0.f;
            u16 hi = f2b(v);
            hv[jj] = hi;
            lv[jj] = f2b(v - b2f(hi));
        }
        *(bf16x8*)&AsH[r * SA + c0] = hv;
        *(bf16x8*)&AsL[r * SA + c0] = lv;
    }
    __syncthreads();

    constexpr int NT = N2 / 64;
    f32x4 acc[2][NT] = {};
    const int wbase = wv * (N2 / 4);
#pragma unroll
    for (int ks = 0; ks < KP / 32; ++ks) {
        bf16x8 a0h = *(const bf16x8*)&AsH[(ln) * SA + ks * 32 + q * 8];
        bf16x8 a1h = *(const bf16x8*)&AsH[(16 + ln) * SA + ks * 32 + q * 8];
        bf16x8 a0l = *(const bf16x8*)&AsL[(ln) * SA + ks * 32 + q * 8];
        bf16x8 a1l = *(const bf16x8*)&AsL[(16 + ln) * SA + ks * 32 + q * 8];
#pragma unroll
        for (int nt = 0; nt < NT; ++nt) {
            size_t wi = (size_t)(wbase + nt * 16 + ln) * KP + ks * 32 + q * 8;
            bf16x8 bh = *(const bf16x8*)&wT[wi];
            bf16x8 bl = *(const bf16x8*)&wT[WSZ + wi];
            acc[0][nt] = mfma16(a0h, bh, acc[0][nt]);
            acc[0][nt] = mfma16(a0h, bl, acc[0][nt]);
            acc[0][nt] = mfma16(a0l, bh, acc[0][nt]);
            acc[1][nt] = mfma16(a1h, bh, acc[1][nt]);
            acc[1][nt] = mfma16(a1h, bl, acc[1][nt]);
            acc[1][nt] = mfma16(a1l, bh, acc[1][nt]);
        }
    }
#pragma unroll
    for (int nt = 0; nt < NT; ++nt) {
        int col = wbase + nt * 16 + ln;
#pragma unroll
        for (int mt = 0; mt < 2; ++mt)
#pragma unroll
            for (int r = 0; r < 4; ++r) {
                size_t row = (size_t)(row0 + mt * 16 + q * 4 + r);
                if (col < CMID)
                    Uf[row * CMID + col] = acc[mt][nt][r] + ba[col];
                else
                    Vb[row * CMID + (col - CMID)] = f2b(acc[mt][nt][r]);
            }
    }
}

// ---------------------------------------------------------------------------
// Edge pool (PTS=2 LOCKED — R8+R11; (256,4) LOCKED — R13 spill at (256,6);
// 1-term Wb validated R15). NTP=4 for edge3 now register-feasible with
// 1-term weights: fixed live = 16 acc f32x4 (64) + 4 weight frags (16) ~ 80
// < 128-reg cap; halves column passes -> halves a-frag LDS reads and per-ks
// addressing (the measured 40% VALUBusy). Tripwire: WRITE_SIZE ~= output.
// Build: pairwise pack via v_perm (round-half-away, <=0.5ulp like RNE).
// ---------------------------------------------------------------------------
template<int CMID, int COUT, bool OUTB, int PTS, int NTP>
__global__ __launch_bounds__(256, 4) void edge_pool(
    const float* __restrict__ Uf, const u16* __restrict__ Vb,
    const int* __restrict__ idx,
    const u16* __restrict__ wbT, const float* __restrict__ bb,
    void* __restrict__ outp)
{
    constexpr int KC = CMID / 32;
    constexpr int C8 = CMID / 8;
    constexpr int NTW = COUT / 64;
    __shared__ __align__(16) u16 hfrag[PTS * 2 * KC * 512];
    __shared__ int nbr[PTS * 32];

    int tid = threadIdx.x, lane = tid & 63, wv = tid >> 6, ln = lane & 15, q = lane >> 4;
    int p0 = blockIdx.x * PTS;

    if (tid < PTS * 32) {
        int pt = tid >> 5, kk = tid & 31;
        int p = p0 + pt;
        nbr[tid] = ((p >> 11) << 11) + (idx[(size_t)p * 32 + kk] & 2047);
    }
    __syncthreads();

    // build h in swizzled fragment order (packed conversion)
    for (int e = tid; e < PTS * 32 * C8; e += 256) {
        int pt = e / (32 * C8), rem = e % (32 * C8), r = rem / C8, c8 = rem % C8;
        const float* U = &Uf[(size_t)(p0 + pt) * CMID + c8 * 8];
        bf16x8 vb = *(const bf16x8*)&Vb[(size_t)nbr[pt * 32 + r] * CMID + c8 * 8];
        u32x4 hq;
#pragma unroll
        for (int jj = 0; jj < 4; ++jj) {
            float f0 = U[2 * jj]     + b2f((u16)vb[2 * jj]);
            float f1 = U[2 * jj + 1] + b2f((u16)vb[2 * jj + 1]);
            f0 = f0 >= 0.f ? f0 : 0.2f * f0;
            f1 = f1 >= 0.f ? f1 : 0.2f * f1;
            u32 a = __float_as_uint(f0) + 0x8000u;
            u32 b = __float_as_uint(f1) + 0x8000u;
            hq[jj] = __builtin_amdgcn_perm(b, a, 0x07060302u);  // hi16(f1)<<16|hi16(f0)
        }
        int mt = r >> 4, lnr = r & 15, ks = c8 >> 2, qq = c8 & 3;
        int slot = qq * 16 + (lnr ^ ((ks << 2) | qq));
        *(u32x4*)&hfrag[(((pt * 2 + mt) * KC + ks) * 64 + slot) * 8] = hq;
    }
    __syncthreads();

    for (int ng = 0; ng < NTW; ng += NTP) {
        f32x4 acc[PTS][2][NTP] = {};  // [pt][mt][nt]
        for (int ks = 0; ks < KC; ++ks) {
            bf16x8 bh[NTP];
#pragma unroll
            for (int nt = 0; nt < NTP; ++nt) {
                size_t wi = ((size_t)((wv * NTW + ng + nt) * KC + ks) * 64 + lane) * 8;
                bh[nt] = *(const bf16x8*)&wbT[wi];
            }
            int slot = q * 16 + (ln ^ ((ks << 2) | q));
#pragma unroll
            for (int pt = 0; pt < PTS; ++pt)
#pragma unroll
                for (int mt = 0; mt < 2; ++mt) {
                    bf16x8 a = *(const bf16x8*)
                        &hfrag[(((pt * 2 + mt) * KC + ks) * 64 + slot) * 8];
#pragma unroll
                    for (int nt = 0; nt < NTP; ++nt)
                        acc[pt][mt][nt] = mfma16(a, bh[nt], acc[pt][mt][nt]);
                }
        }
        // per-point max over 32 rows, bias+lrelu, store (frees accs)
#pragma unroll
        for (int pt = 0; pt < PTS; ++pt)
#pragma unroll
            for (int nt = 0; nt < NTP; ++nt) {
                int col = wv * (COUT / 4) + (ng + nt) * 16 + ln;
                float m = acc[pt][0][nt][0];
#pragma unroll
                for (int r = 1; r < 4; ++r) m = fmaxf(m, acc[pt][0][nt][r]);
#pragma unroll
                for (int r = 0; r < 4; ++r) m = fmaxf(m, acc[pt][1][nt][r]);
                m = fmaxf(m, __shfl_xor(m, 16));
                m = fmaxf(m, __shfl_xor(m, 32));
                if (q == 0) {
                    float v = m + bb[col];
                    v = v >= 0.f ? v : 0.2f * v;
                    if constexpr (OUTB)
                        ((u16*)outp)[(size_t)(p0 + pt) * COUT + col] = f2b(v);
                    else
                        ((float*)outp)[(size_t)(p0 + pt) * COUT + col] = v;
                }
            }
    }
}

// ---------------------------------------------------------------------------
// head1: concat[x1(f32,64)|x2(f32,128)|x3(bf16,512)] (704) -> 512, lrelu,
// out bf16. 32 rows/WG, K tiled 2x352. W hi-plane only (R15/R16 validated);
// A-side split kept for the f32 x1/x2 columns.
// ---------------------------------------------------------------------------
__global__ __launch_bounds__(256) void head1(
    const float* __restrict__ x1, const float* __restrict__ x2,
    const u16* __restrict__ x3,
    const u16* __restrict__ wT, const float* __restrict__ bias,
    u16* __restrict__ out)
{
    constexpr int KD = 704, KT = 352, SA = 360, COUT = 512;
    __shared__ __align__(16) u16 AsH[32 * SA];
    __shared__ __align__(16) u16 AsL[32 * SA];
    int row0 = blockIdx.x * 32;
    int tid = threadIdx.x, lane = tid & 63, wv = tid >> 6, ln = lane & 15, q = lane >> 4;

    f32x4 acc[2][8] = {};
    const int wbase = wv * 128;

    for (int ph = 0; ph < 2; ++ph) {
        if (ph) __syncthreads();
        for (int e = tid; e < 32 * 44; e += 256) {
            int r = e / 44, c8l = e % 44;
            int c = ph * KT + c8l * 8;
            int g = row0 + r;
            int a = r * SA + c8l * 8;
            if (c < 192) {
                const float* src = (c < 64) ? &x1[(size_t)g * 64 + c]
                                            : &x2[(size_t)g * 128 + (c - 64)];
                bf16x8 hv, lv;
#pragma unroll
                for (int jj = 0; jj < 8; ++jj) {
                    float v = src[jj];
                    u16 hi = f2b(v);
                    hv[jj] = hi;
                    lv[jj] = f2b(v - b2f(hi));
                }
                *(bf16x8*)&AsH[a] = hv;
                *(bf16x8*)&AsL[a] = lv;
            } else {
                *(bf16x8*)&AsH[a] = *(const bf16x8*)&x3[(size_t)g * 512 + (c - 192)];
                bf16x8 z = {0, 0, 0, 0, 0, 0, 0, 0};
                *(bf16x8*)&AsL[a] = z;
            }
        }
        __syncthreads();
        for (int ks = 0; ks < 11; ++ks) {
            int gk = ph * 11 + ks;
            bool t3 = (gk < 6);
            bf16x8 a0h = *(const bf16x8*)&AsH[(ln) * SA + ks * 32 + q * 8];
            bf16x8 a1h = *(const bf16x8*)&AsH[(16 + ln) * SA + ks * 32 + q * 8];
            bf16x8 a0l = *(const bf16x8*)&AsL[(ln) * SA + ks * 32 + q * 8];
            bf16x8 a1l = *(const bf16x8*)&AsL[(16 + ln) * SA + ks * 32 + q * 8];
#pragma unroll
            for (int nt = 0; nt < 8; ++nt) {
                size_t wi = (size_t)(wbase + nt * 16 + ln) * KD + gk * 32 + q * 8;
                bf16x8 bh = *(const bf16x8*)&wT[wi];
                acc[0][nt] = mfma16(a0h, bh, acc[0][nt]);
                acc[1][nt] = mfma16(a1h, bh, acc[1][nt]);
                if (t3) {
                    acc[0][nt] = mfma16(a0l, bh, acc[0][nt]);
                    acc[1][nt] = mfma16(a1l, bh, acc[1][nt]);
                }
            }
        }
    }
#pragma unroll
    for (int nt = 0; nt < 8; ++nt) {
        int col = wbase + nt * 16 + ln;
        float bv = bias[col];
#pragma unroll
        for (int mt = 0; mt < 2; ++mt)
#pragma unroll
            for (int r = 0; r < 4; ++r) {
                float v = acc[mt][nt][r] + bv;
                v = v >= 0.f ? v : 0.2f * v;
                out[(size_t)(row0 + mt * 16 + q * 4 + r) * COUT + col] = f2b(v);
            }
    }
}

// ---------------------------------------------------------------------------
// head_bf: A bf16 [16384][K] -> COUT, W hi-plane only, lrelu, out bf16.
// ---------------------------------------------------------------------------
template<int K, int COUT>
__global__ __launch_bounds__(256) void head_bf(
    const u16* __restrict__ A, const u16* __restrict__ wT,
    const float* __restrict__ bias, u16* __restrict__ out)
{
    constexpr int SA = K + 8;
    __shared__ __align__(16) u16 As[32 * SA];
    int row0 = blockIdx.x * 32;
    int tid = threadIdx.x, lane = tid & 63, wv = tid >> 6, ln = lane & 15, q = lane >> 4;

    for (int e = tid; e < 32 * (K / 8); e += 256) {
        int r = e / (K / 8), c0 = (e % (K / 8)) * 8;
        *(bf16x8*)&As[r * SA + c0] = *(const bf16x8*)&A[(size_t)(row0 + r) * K + c0];
    }
    __syncthreads();

    constexpr int NT = COUT / 64;
    f32x4 acc[2][NT] = {};
    const int wbase = wv * (COUT / 4);
    for (int ks = 0; ks < K / 32; ++ks) {
        bf16x8 a0 = *(const bf16x8*)&As[(ln) * SA + ks * 32 + q * 8];
        bf16x8 a1 = *(const bf16x8*)&As[(16 + ln) * SA + ks * 32 + q * 8];
#pragma unroll
        for (int nt = 0; nt < NT; ++nt) {
            size_t wi = (size_t)(wbase + nt * 16 + ln) * K + ks * 32 + q * 8;
            bf16x8 bh = *(const bf16x8*)&wT[wi];
            acc[0][nt] = mfma16(a0, bh, acc[0][nt]);
            acc[1][nt] = mfma16(a1, bh, acc[1][nt]);
        }
    }
#pragma unroll
    for (int nt = 0; nt < NT; ++nt) {
        int col = wbase + nt * 16 + ln;
        float bv = bias[col];
#pragma unroll
        for (int mt = 0; mt < 2; ++mt)
#pragma unroll
            for (int r = 0; r < 4; ++r) {
                float v = acc[mt][nt][r] + bv;
                v = v >= 0.f ? v : 0.2f * v;
                out[(size_t)(row0 + mt * 16 + q * 4 + r) * COUT + col] = f2b(v);
            }
    }
}

// ---------------------------------------------------------------------------
// head3: A bf16 [16384][256] -> 12 (N padded 16), W hi-plane only, out f32.
// ---------------------------------------------------------------------------
__global__ __launch_bounds__(256) void head_gemm3(
    const u16* __restrict__ A, const u16* __restrict__ wT,
    const float* __restrict__ bias, float* __restrict__ out)
{
    int tid = threadIdx.x, lane = tid & 63, wv = tid >> 6, ln = lane & 15, q = lane >> 4;
    int row0 = (blockIdx.x * 4 + wv) * 32;
    f32x4 acc[2] = {};
#pragma unroll
    for (int ks = 0; ks < 8; ++ks) {
        bf16x8 a0 = *(const bf16x8*)&A[(size_t)(row0 + ln) * 256 + ks * 32 + q * 8];
        bf16x8 a1 = *(const bf16x8*)&A[(size_t)(row0 + 16 + ln) * 256 + ks * 32 + q * 8];
        size_t wi = (size_t)ln * 256 + ks * 32 + q * 8;
        bf16x8 bh = *(const bf16x8*)&wT[wi];
        acc[0] = mfma16(a0, bh, acc[0]);
        acc[1] = mfma16(a1, bh, acc[1]);
    }
    if (ln < 12) {
        float bv = bias[ln];
#pragma unroll
        for (int mt = 0; mt < 2; ++mt)
#pragma unroll
            for (int r = 0; r < 4; ++r)
                out[(size_t)(row0 + mt * 16 + q * 4 + r) * 12 + ln] = acc[mt][r] + bv;
    }
}

// ---------------------------------------------------------------------------
// Workspace (peak 50,708,480 B = 48.4 MB):
//   [0,        2473984)  split weights
//   [2473984,  4571136)  idxb
//   [4571136,  8765440)  x1 f32      (dead after head1; h2 bf16 overlays)
//   [8765440, 17154048)  x2 f32      (dead after head1)
//   [17154048,33931264)  Uf f32 (<=8MB) @ +0, Vb bf16 (<=4MB) @ +8MB;
//                        h1 bf16 (16MB) overlays whole region after edge3
//   [33931264,50708480)  x3 bf16
// ---------------------------------------------------------------------------
extern "C" void kernel_launch(void* const* d_in, const int* in_sizes, int n_in,
                              void* d_out, int out_size, void* d_ws, size_t ws_size,
                              hipStream_t stream)
{
    (void)in_sizes; (void)n_in; (void)out_size; (void)ws_size;
    const float* x   = (const float*)d_in[0];
    const float* pos = (const float*)d_in[1];
    const float* w1a = (const float*)d_in[2];  const float* b1a = (const float*)d_in[3];
    const float* w1b = (const float*)d_in[4];  const float* b1b = (const float*)d_in[5];
    const float* w2a = (const float*)d_in[6];  const float* b2a = (const float*)d_in[7];
    const float* w2b = (const float*)d_in[8];  const float* b2b = (const float*)d_in[9];
    const float* w3a = (const float*)d_in[10]; const float* b3a = (const float*)d_in[11];
    const float* w3b = (const float*)d_in[12]; const float* b3b = (const float*)d_in[13];
    const float* wf1 = (const float*)d_in[14]; const float* bf1 = (const float*)d_in[15];
    const float* wf2 = (const float*)d_in[16]; const float* bf2 = (const float*)d_in[17];
    const float* wf3 = (const float*)d_in[18]; const float* bf3 = (const float*)d_in[19];

    char* ws = (char*)d_ws;
    u16* t1uv = (u16*)(ws + 0);
    u16* t2uv = (u16*)(ws + 16384);
    u16* t3uv = (u16*)(ws + 49152);
    u16* t1b  = (u16*)(ws + 180224);
    u16* t2b  = (u16*)(ws + 196608);
    u16* t3b  = (u16*)(ws + 229376);
    u16* tf1  = (u16*)(ws + 491520);
    u16* tf2  = (u16*)(ws + 1933312);
    u16* tf3  = (u16*)(ws + 2457600);
    int*   idxb = (int*)(ws + 2473984);
    float* x1 = (float*)(ws + 4571136);
    float* x2 = (float*)(ws + 8765440);
    float* Uf = (float*)(ws + 17154048);           // <= 8 MB (edge3)
    u16*   Vb = (u16*)(ws + 17154048 + 8388608);   // <= 4 MB (edge3)
    u16*   x3 = (u16*)(ws + 33931264);
    u16*   h1 = (u16*)(ws + 17154048);    // overlays Uf/Vb after edge3
    u16*   h2 = (u16*)(ws + 4571136);     // overlays x1/x2 after head1

    prep_weights<<<2416, 256, 0, stream>>>(w1a, w1b, w2a, w2b, w3a, w3b, wf1, wf2, wf3,
                                           t1uv, t2uv, t3uv, t1b, t2b, t3b, tf1, tf2, tf3);
    knn_kernel<<<4096, 256, 0, stream>>>(pos, idxb);
    uv_gemm<  3, 32, 128><<<512, 256, 0, stream>>>(x,  t1uv, b1a, Uf, Vb);
    edge_pool< 64,  64, false, 2, 1><<<8192, 256, 0, stream>>>(Uf, Vb, idxb, t1b, b1b, x1);
    uv_gemm< 64, 64, 128><<<512, 256, 0, stream>>>(x1, t2uv, b2a, Uf, Vb);
    edge_pool< 64, 128, false, 2, 2><<<8192, 256, 0, stream>>>(Uf, Vb, idxb, t2b, b2b, x2);
    uv_gemm<128, 128, 256><<<512, 256, 0, stream>>>(x2, t3uv, b3a, Uf, Vb);
    edge_pool<128, 512, true, 2, 4><<<8192, 256, 0, stream>>>(Uf, Vb, idxb, t3b, b3b, x3);
    head1<<<512, 256, 0, stream>>>(x1, x2, x3, tf1, bf1, h1);
    head_bf<512, 256><<<512, 256, 0, stream>>>(h1, tf2, bf2, h2);
    head_gemm3<<<128, 256, 0, stream>>>(h2, tf3, bf3, (float*)d_out);
}

// Round 18
// 432.157 us; speedup vs baseline: 1.0408x; 1.0408x over previous
//
#include <hip/hip_runtime.h>

typedef unsigned short u16;
typedef unsigned int u32;
typedef unsigned long long u64;
typedef short bf16x8 __attribute__((ext_vector_type(8)));
typedef float f32x4 __attribute__((ext_vector_type(4)));
typedef u32 u32x4 __attribute__((ext_vector_type(4)));

__device__ __forceinline__ float b2f(u16 u) {
    return __uint_as_float(((u32)u) << 16);
}
__device__ __forceinline__ u16 f2b(float f) {  // RNE
    u32 u = __float_as_uint(f);
    u32 r = u + 0x7fffu + ((u >> 16) & 1u);
    return (u16)(r >> 16);
}
__device__ __forceinline__ f32x4 mfma16(bf16x8 a, bf16x8 b, f32x4 c) {
    return __builtin_amdgcn_mfma_f32_16x16x32_bf16(a, b, c, 0, 0, 0);
}

// ---------------------------------------------------------------------------
// prep: weights. seg -> W^T[n][k] row-major split bf16 (hi, lo planes).
// seg_bf -> MFMA B-fragment order: [tile][ks][lane][8]. seg_uv -> stacked
// [(Wa1-Wa2)^T ; Wa2^T].
// ---------------------------------------------------------------------------
template<int NP, int KP, int R, int C>
__device__ __forceinline__ bool seg(int t, int base, const float* src, u16* dst) {
    int r = t - base;
    if (r < 0) return true;
    constexpr int RNG = NP * KP;
    if (r >= RNG) return false;
    int n = r / KP, k = r - n * KP;
    float v = (k < R && n < C) ? src[k * C + n] : 0.f;
    u16 hi = f2b(v);
    dst[r] = hi;
    dst[RNG + r] = f2b(v - b2f(hi));
    return true;
}
template<int NP, int KP, int R, int C>
__device__ __forceinline__ bool seg_bf(int t, int base, const float* src, u16* dst) {
    int r = t - base;
    if (r < 0) return true;
    constexpr int RNG = NP * KP;
    if (r >= RNG) return false;
    constexpr int KC = KP / 32;
    int j = r & 7, s = r >> 3;
    int lanei = s & 63;
    int ks = (s >> 6) % KC, tile = (s >> 6) / KC;
    int n = tile * 16 + (lanei & 15);
    int k = ks * 32 + (lanei >> 4) * 8 + j;
    float v = (k < R && n < C) ? src[k * C + n] : 0.f;
    u16 hi = f2b(v);
    dst[r] = hi;
    dst[RNG + r] = f2b(v - b2f(hi));
    return true;
}
template<int CMID, int CIN, int KP>
__device__ __forceinline__ bool seg_uv(int t, int base, const float* wa, u16* dst) {
    int r = t - base;
    if (r < 0) return true;
    constexpr int RNG = 2 * CMID * KP;
    if (r >= RNG) return false;
    int n = r / KP, k = r - n * KP;
    float v = 0.f;
    if (k < CIN) {
        if (n < CMID) v = wa[k * CMID + n] - wa[(CIN + k) * CMID + n];
        else          v = wa[(CIN + k) * CMID + (n - CMID)];
    }
    u16 hi = f2b(v);
    dst[r] = hi;
    dst[RNG + r] = f2b(v - b2f(hi));
    return true;
}

__global__ __launch_bounds__(256) void prep_weights(
    const float* w1a, const float* w1b, const float* w2a, const float* w2b,
    const float* w3a, const float* w3b, const float* wf1, const float* wf2,
    const float* wf3,
    u16* t1uv, u16* t2uv, u16* t3uv, u16* t1b, u16* t2b, u16* t3b,
    u16* tf1, u16* tf2, u16* tf3)
{
    int t = blockIdx.x * 256 + threadIdx.x;
    if (seg_uv< 64,   3,  32>(t,      0, w1a, t1uv)) return;
    if (seg_uv< 64,  64,  64>(t,   4096, w2a, t2uv)) return;
    if (seg_uv<128, 128, 128>(t,  12288, w3a, t3uv)) return;
    if (seg_bf< 64,  64,  64,  64>(t,  45056, w1b, t1b)) return;
    if (seg_bf<128,  64,  64, 128>(t,  49152, w2b, t2b)) return;
    if (seg_bf<512, 128, 128, 512>(t,  57344, w3b, t3b)) return;
    if (seg<512, 704, 704, 512>(t, 122880, wf1, tf1)) return;
    if (seg<256, 512, 512, 256>(t, 483328, wf2, tf2)) return;
    if (seg< 16, 256, 256,  12>(t, 614400, wf3, tf3)) return;
}

// ---------------------------------------------------------------------------
// kNN: one WAVE per point. Key = (orderable(d2) << 11) | idx, exact in f64
// (43 bits). Two-phase exact selection (R10-proven):
//  Phase 1: T = 32nd-smallest of the 64 lane-minima (bitonic across lanes).
//  Phase 2: ballot-compact keys <= T into LDS (cap 256), exact ascending
//    min-above-last on 4 keys/lane. Gate -> fallback (identical output).
// ---------------------------------------------------------------------------
__global__ __launch_bounds__(256) void knn_kernel(const float* __restrict__ pos,
                                                  int* __restrict__ idxout)
{
    int tid = threadIdx.x, lane = tid & 63, wv = tid >> 6;
    int p = blockIdx.x * 4 + wv;
    int b = p >> 11, n = p & 2047;
    __shared__ double cand[4][256];
    const float* pb = pos + (size_t)b * 2048 * 3;
    float pn0 = pb[n * 3 + 0], pn1 = pb[n * 3 + 1], pn2 = pb[n * 3 + 2];
    float sqn = __fadd_rn(__fadd_rn(__fmul_rn(pn0, pn0), __fmul_rn(pn1, pn1)),
                          __fmul_rn(pn2, pn2));
    double kd[32];
#pragma unroll
    for (int j = 0; j < 32; ++j) {
        int m = lane + j * 64;
        float q0 = pb[m * 3 + 0], q1 = pb[m * 3 + 1], q2 = pb[m * 3 + 2];
        float sqm = __fadd_rn(__fadd_rn(__fmul_rn(q0, q0), __fmul_rn(q1, q1)),
                              __fmul_rn(q2, q2));
        float dot = __fadd_rn(__fadd_rn(__fmul_rn(pn0, q0), __fmul_rn(pn1, q1)),
                              __fmul_rn(pn2, q2));
        float d2 = __fadd_rn(__fsub_rn(sqn, __fmul_rn(2.0f, dot)), sqm);
        u32 u = __float_as_uint(d2);
        u = (u & 0x80000000u) ? ~u : (u | 0x80000000u);  // orderable
        kd[j] = (double)((((u64)u) << 11) | (u32)m);
    }

    // Phase 1: lane-minima, bitonic sort across 64 lanes, T = 32nd smallest.
    double lmin = kd[0];
#pragma unroll
    for (int j = 1; j < 32; ++j) lmin = fmin(lmin, kd[j]);
    double v = lmin;
#pragma unroll
    for (int k = 2; k <= 64; k <<= 1) {
#pragma unroll
        for (int j2 = k >> 1; j2 > 0; j2 >>= 1) {
            double o = __shfl_xor(v, j2);
            bool up = ((lane & k) == 0);
            bool low = ((lane & j2) == 0);
            double mn = fmin(v, o), mx = fmax(v, o);
            v = (up == low) ? mn : mx;
        }
    }
    double T = __shfl(v, 31);

    // Phase 2: pad + ballot-compact keys <= T into LDS.
#pragma unroll
    for (int s = 0; s < 4; ++s) cand[wv][lane + s * 64] = 1e300;
    int base = 0;
#pragma unroll
    for (int j = 0; j < 32; ++j) {
        bool pred = (kd[j] <= T);
        u64 bal = __ballot(pred);
        int prefix = (int)__popcll(bal & ((1ull << lane) - 1ull));
        int slot = base + prefix;
        if (pred && slot < 256) cand[wv][slot] = kd[j];
        base += (int)__popcll(bal);
    }

    if (base >= 32 && base <= 256) {
        double kc[4];
#pragma unroll
        for (int j = 0; j < 4; ++j) kc[j] = cand[wv][lane * 4 + j];
        double last = -1.0;
        for (int it = 0; it < 32; ++it) {
            double lm = 1e300;
#pragma unroll
            for (int j = 0; j < 4; ++j) {
                double t = kc[j];
                lm = fmin(lm, (t > last) ? t : 1e300);
            }
#pragma unroll
            for (int off = 32; off; off >>= 1)
                lm = fmin(lm, __shfl_xor(lm, off));
            if (lane == 0) idxout[(size_t)p * 32 + it] = (int)(((u64)lm) & 2047u);
            last = lm;
        }
    } else {
        // Fallback: exact full-register selection (R9 path).
        double last = -1.0;
        for (int it = 0; it < 32; ++it) {
            double lm0 = 1e300, lm1 = 1e300;
#pragma unroll
            for (int j = 0; j < 32; j += 2) {
                double t0 = kd[j], t1 = kd[j + 1];
                lm0 = fmin(lm0, (t0 > last) ? t0 : 1e300);
                lm1 = fmin(lm1, (t1 > last) ? t1 : 1e300);
            }
            double lm = fmin(lm0, lm1);
#pragma unroll
            for (int off = 32; off; off >>= 1)
                lm = fmin(lm, __shfl_xor(lm, off));
            if (lane == 0) idxout[(size_t)p * 32 + it] = (int)(((u64)lm) & 2047u);
            last = lm;
        }
    }
}

// ---------------------------------------------------------------------------
// UV GEMM: U[n][c] = x@(Wa1-Wa2)+ba  (f32, exact, read once per point);
//          V[n][c] = x@Wa2           (bf16, gathered 32x -> half traffic).
// A f32 -> split LDS, 3-term MFMA vs split weights (defines U/V precision).
// ---------------------------------------------------------------------------
template<int K, int KP, int N2>
__global__ __launch_bounds__(256) void uv_gemm(
    const float* __restrict__ xin, const u16* __restrict__ wT,
    const float* __restrict__ ba, float* __restrict__ Uf, u16* __restrict__ Vb)
{
    constexpr int SA = KP + 8;
    constexpr int WSZ = N2 * KP;
    constexpr int CMID = N2 / 2;
    __shared__ __align__(16) u16 AsH[32 * SA];
    __shared__ __align__(16) u16 AsL[32 * SA];
    int row0 = blockIdx.x * 32;
    int tid = threadIdx.x, lane = tid & 63, wv = tid >> 6, ln = lane & 15, q = lane >> 4;

    for (int e = tid; e < 32 * (KP / 8); e += 256) {
        int r = e / (KP / 8), c0 = (e % (KP / 8)) * 8;
        bf16x8 hv, lv;
#pragma unroll
        for (int jj = 0; jj < 8; ++jj) {
            int c = c0 + jj;
            float v = (c < K) ? xin[(size_t)(row0 + r) * K + c] : 0.f;
            u16 hi = f2b(v);
            hv[jj] = hi;
            lv[jj] = f2b(v - b2f(hi));
        }
        *(bf16x8*)&AsH[r * SA + c0] = hv;
        *(bf16x8*)&AsL[r * SA + c0] = lv;
    }
    __syncthreads();

    constexpr int NT = N2 / 64;
    f32x4 acc[2][NT] = {};
    const int wbase = wv * (N2 / 4);
#pragma unroll
    for (int ks = 0; ks < KP / 32; ++ks) {
        bf16x8 a0h = *(const bf16x8*)&AsH[(ln) * SA + ks * 32 + q * 8];
        bf16x8 a1h = *(const bf16x8*)&AsH[(16 + ln) * SA + ks * 32 + q * 8];
        bf16x8 a0l = *(const bf16x8*)&AsL[(ln) * SA + ks * 32 + q * 8];
        bf16x8 a1l = *(const bf16x8*)&AsL[(16 + ln) * SA + ks * 32 + q * 8];
#pragma unroll
        for (int nt = 0; nt < NT; ++nt) {
            size_t wi = (size_t)(wbase + nt * 16 + ln) * KP + ks * 32 + q * 8;
            bf16x8 bh = *(const bf16x8*)&wT[wi];
            bf16x8 bl = *(const bf16x8*)&wT[WSZ + wi];
            acc[0][nt] = mfma16(a0h, bh, acc[0][nt]);
            acc[0][nt] = mfma16(a0h, bl, acc[0][nt]);
            acc[0][nt] = mfma16(a0l, bh, acc[0][nt]);
            acc[1][nt] = mfma16(a1h, bh, acc[1][nt]);
            acc[1][nt] = mfma16(a1h, bl, acc[1][nt]);
            acc[1][nt] = mfma16(a1l, bh, acc[1][nt]);
        }
    }
#pragma unroll
    for (int nt = 0; nt < NT; ++nt) {
        int col = wbase + nt * 16 + ln;
#pragma unroll
        for (int mt = 0; mt < 2; ++mt)
#pragma unroll
            for (int r = 0; r < 4; ++r) {
                size_t row = (size_t)(row0 + mt * 16 + q * 4 + r);
                if (col < CMID)
                    Uf[row * CMID + col] = acc[mt][nt][r] + ba[col];
                else
                    Vb[row * CMID + (col - CMID)] = f2b(acc[mt][nt][r]);
            }
    }
}

// ---------------------------------------------------------------------------
// Edge pool — LOCKED config (R16, 432us proven):
//   PTS=2 (PTS=4 spills: R8+R11), (256,4) (R13: (256,6) spills),
//   NTP<=2 (R17: NTP=4 spills), 1-term Wb (R15: absmax unchanged).
// Register law at (256,4): live state <= ~8 acc f32x4 + 2 weight frags.
// h = lrelu(U_f32+V_bf16) -> bf16 XOR-swizzled A-frag order in LDS (packed
// v_perm conversion, round-half-away <=0.5ulp); column-group passes of NTP
// tiles, Wb lane-contiguous (B-frag order); per-point max over 32 rows,
// bias+lrelu. Tripwire: WRITE_SIZE ~= output.
// ---------------------------------------------------------------------------
template<int CMID, int COUT, bool OUTB, int PTS, int NTP>
__global__ __launch_bounds__(256, 4) void edge_pool(
    const float* __restrict__ Uf, const u16* __restrict__ Vb,
    const int* __restrict__ idx,
    const u16* __restrict__ wbT, const float* __restrict__ bb,
    void* __restrict__ outp)
{
    constexpr int KC = CMID / 32;
    constexpr int C8 = CMID / 8;
    constexpr int NTW = COUT / 64;
    __shared__ __align__(16) u16 hfrag[PTS * 2 * KC * 512];
    __shared__ int nbr[PTS * 32];

    int tid = threadIdx.x, lane = tid & 63, wv = tid >> 6, ln = lane & 15, q = lane >> 4;
    int p0 = blockIdx.x * PTS;

    if (tid < PTS * 32) {
        int pt = tid >> 5, kk = tid & 31;
        int p = p0 + pt;
        nbr[tid] = ((p >> 11) << 11) + (idx[(size_t)p * 32 + kk] & 2047);
    }
    __syncthreads();

    // build h in swizzled fragment order (packed conversion)
    for (int e = tid; e < PTS * 32 * C8; e += 256) {
        int pt = e / (32 * C8), rem = e % (32 * C8), r = rem / C8, c8 = rem % C8;
        const float* U = &Uf[(size_t)(p0 + pt) * CMID + c8 * 8];
        bf16x8 vb = *(const bf16x8*)&Vb[(size_t)nbr[pt * 32 + r] * CMID + c8 * 8];
        u32x4 hq;
#pragma unroll
        for (int jj = 0; jj < 4; ++jj) {
            float f0 = U[2 * jj]     + b2f((u16)vb[2 * jj]);
            float f1 = U[2 * jj + 1] + b2f((u16)vb[2 * jj + 1]);
            f0 = f0 >= 0.f ? f0 : 0.2f * f0;
            f1 = f1 >= 0.f ? f1 : 0.2f * f1;
            u32 a = __float_as_uint(f0) + 0x8000u;
            u32 b = __float_as_uint(f1) + 0x8000u;
            hq[jj] = __builtin_amdgcn_perm(b, a, 0x07060302u);  // hi16(f1)<<16|hi16(f0)
        }
        int mt = r >> 4, lnr = r & 15, ks = c8 >> 2, qq = c8 & 3;
        int slot = qq * 16 + (lnr ^ ((ks << 2) | qq));
        *(u32x4*)&hfrag[(((pt * 2 + mt) * KC + ks) * 64 + slot) * 8] = hq;
    }
    __syncthreads();

    for (int ng = 0; ng < NTW; ng += NTP) {
        f32x4 acc[PTS][2][NTP] = {};  // [pt][mt][nt]
        for (int ks = 0; ks < KC; ++ks) {
            bf16x8 bh[NTP];
#pragma unroll
            for (int nt = 0; nt < NTP; ++nt) {
                size_t wi = ((size_t)((wv * NTW + ng + nt) * KC + ks) * 64 + lane) * 8;
                bh[nt] = *(const bf16x8*)&wbT[wi];
            }
            int slot = q * 16 + (ln ^ ((ks << 2) | q));
#pragma unroll
            for (int pt = 0; pt < PTS; ++pt)
#pragma unroll
                for (int mt = 0; mt < 2; ++mt) {
                    bf16x8 a = *(const bf16x8*)
                        &hfrag[(((pt * 2 + mt) * KC + ks) * 64 + slot) * 8];
#pragma unroll
                    for (int nt = 0; nt < NTP; ++nt)
                        acc[pt][mt][nt] = mfma16(a, bh[nt], acc[pt][mt][nt]);
                }
        }
        // per-point max over 32 rows, bias+lrelu, store (frees accs)
#pragma unroll
        for (int pt = 0; pt < PTS; ++pt)
#pragma unroll
            for (int nt = 0; nt < NTP; ++nt) {
                int col = wv * (COUT / 4) + (ng + nt) * 16 + ln;
                float m = acc[pt][0][nt][0];
#pragma unroll
                for (int r = 1; r < 4; ++r) m = fmaxf(m, acc[pt][0][nt][r]);
#pragma unroll
                for (int r = 0; r < 4; ++r) m = fmaxf(m, acc[pt][1][nt][r]);
                m = fmaxf(m, __shfl_xor(m, 16));
                m = fmaxf(m, __shfl_xor(m, 32));
                if (q == 0) {
                    float v = m + bb[col];
                    v = v >= 0.f ? v : 0.2f * v;
                    if constexpr (OUTB)
                        ((u16*)outp)[(size_t)(p0 + pt) * COUT + col] = f2b(v);
                    else
                        ((float*)outp)[(size_t)(p0 + pt) * COUT + col] = v;
                }
            }
    }
}

// ---------------------------------------------------------------------------
// head1: concat[x1(f32,64)|x2(f32,128)|x3(bf16,512)] (704) -> 512, lrelu,
// out bf16. 32 rows/WG, K tiled 2x352. W hi-plane only (R15/R16 validated);
// A-side split kept for the f32 x1/x2 columns.
// ---------------------------------------------------------------------------
__global__ __launch_bounds__(256) void head1(
    const float* __restrict__ x1, const float* __restrict__ x2,
    const u16* __restrict__ x3,
    const u16* __restrict__ wT, const float* __restrict__ bias,
    u16* __restrict__ out)
{
    constexpr int KD = 704, KT = 352, SA = 360, COUT = 512;
    __shared__ __align__(16) u16 AsH[32 * SA];
    __shared__ __align__(16) u16 AsL[32 * SA];
    int row0 = blockIdx.x * 32;
    int tid = threadIdx.x, lane = tid & 63, wv = tid >> 6, ln = lane & 15, q = lane >> 4;

    f32x4 acc[2][8] = {};
    const int wbase = wv * 128;

    for (int ph = 0; ph < 2; ++ph) {
        if (ph) __syncthreads();
        for (int e = tid; e < 32 * 44; e += 256) {
            int r = e / 44, c8l = e % 44;
            int c = ph * KT + c8l * 8;
            int g = row0 + r;
            int a = r * SA + c8l * 8;
            if (c < 192) {
                const float* src = (c < 64) ? &x1[(size_t)g * 64 + c]
                                            : &x2[(size_t)g * 128 + (c - 64)];
                bf16x8 hv, lv;
#pragma unroll
                for (int jj = 0; jj < 8; ++jj) {
                    float v = src[jj];
                    u16 hi = f2b(v);
                    hv[jj] = hi;
                    lv[jj] = f2b(v - b2f(hi));
                }
                *(bf16x8*)&AsH[a] = hv;
                *(bf16x8*)&AsL[a] = lv;
            } else {
                *(bf16x8*)&AsH[a] = *(const bf16x8*)&x3[(size_t)g * 512 + (c - 192)];
                bf16x8 z = {0, 0, 0, 0, 0, 0, 0, 0};
                *(bf16x8*)&AsL[a] = z;
            }
        }
        __syncthreads();
        for (int ks = 0; ks < 11; ++ks) {
            int gk = ph * 11 + ks;
            bool t3 = (gk < 6);
            bf16x8 a0h = *(const bf16x8*)&AsH[(ln) * SA + ks * 32 + q * 8];
            bf16x8 a1h = *(const bf16x8*)&AsH[(16 + ln) * SA + ks * 32 + q * 8];
            bf16x8 a0l = *(const bf16x8*)&AsL[(ln) * SA + ks * 32 + q * 8];
            bf16x8 a1l = *(const bf16x8*)&AsL[(16 + ln) * SA + ks * 32 + q * 8];
#pragma unroll
            for (int nt = 0; nt < 8; ++nt) {
                size_t wi = (size_t)(wbase + nt * 16 + ln) * KD + gk * 32 + q * 8;
                bf16x8 bh = *(const bf16x8*)&wT[wi];
                acc[0][nt] = mfma16(a0h, bh, acc[0][nt]);
                acc[1][nt] = mfma16(a1h, bh, acc[1][nt]);
                if (t3) {
                    acc[0][nt] = mfma16(a0l, bh, acc[0][nt]);
                    acc[1][nt] = mfma16(a1l, bh, acc[1][nt]);
                }
            }
        }
    }
#pragma unroll
    for (int nt = 0; nt < 8; ++nt) {
        int col = wbase + nt * 16 + ln;
        float bv = bias[col];
#pragma unroll
        for (int mt = 0; mt < 2; ++mt)
#pragma unroll
            for (int r = 0; r < 4; ++r) {
                float v = acc[mt][nt][r] + bv;
                v = v >= 0.f ? v : 0.2f * v;
                out[(size_t)(row0 + mt * 16 + q * 4 + r) * COUT + col] = f2b(v);
            }
    }
}

// ---------------------------------------------------------------------------
// head_bf: A bf16 [16384][K] -> COUT, W hi-plane only, lrelu, out bf16.
// ---------------------------------------------------------------------------
template<int K, int COUT>
__global__ __launch_bounds__(256) void head_bf(
    const u16* __restrict__ A, const u16* __restrict__ wT,
    const float* __restrict__ bias, u16* __restrict__ out)
{
    constexpr int SA = K + 8;
    __shared__ __align__(16) u16 As[32 * SA];
    int row0 = blockIdx.x * 32;
    int tid = threadIdx.x, lane = tid & 63, wv = tid >> 6, ln = lane & 15, q = lane >> 4;

    for (int e = tid; e < 32 * (K / 8); e += 256) {
        int r = e / (K / 8), c0 = (e % (K / 8)) * 8;
        *(bf16x8*)&As[r * SA + c0] = *(const bf16x8*)&A[(size_t)(row0 + r) * K + c0];
    }
    __syncthreads();

    constexpr int NT = COUT / 64;
    f32x4 acc[2][NT] = {};
    const int wbase = wv * (COUT / 4);
    for (int ks = 0; ks < K / 32; ++ks) {
        bf16x8 a0 = *(const bf16x8*)&As[(ln) * SA + ks * 32 + q * 8];
        bf16x8 a1 = *(const bf16x8*)&As[(16 + ln) * SA + ks * 32 + q * 8];
#pragma unroll
        for (int nt = 0; nt < NT; ++nt) {
            size_t wi = (size_t)(wbase + nt * 16 + ln) * K + ks * 32 + q * 8;
            bf16x8 bh = *(const bf16x8*)&wT[wi];
            acc[0][nt] = mfma16(a0, bh, acc[0][nt]);
            acc[1][nt] = mfma16(a1, bh, acc[1][nt]);
        }
    }
#pragma unroll
    for (int nt = 0; nt < NT; ++nt) {
        int col = wbase + nt * 16 + ln;
        float bv = bias[col];
#pragma unroll
        for (int mt = 0; mt < 2; ++mt)
#pragma unroll
            for (int r = 0; r < 4; ++r) {
                float v = acc[mt][nt][r] + bv;
                v = v >= 0.f ? v : 0.2f * v;
                out[(size_t)(row0 + mt * 16 + q * 4 + r) * COUT + col] = f2b(v);
            }
    }
}

// ---------------------------------------------------------------------------
// head3: A bf16 [16384][256] -> 12 (N padded 16), W hi-plane only, out f32.
// ---------------------------------------------------------------------------
__global__ __launch_bounds__(256) void head_gemm3(
    const u16* __restrict__ A, const u16* __restrict__ wT,
    const float* __restrict__ bias, float* __restrict__ out)
{
    int tid = threadIdx.x, lane = tid & 63, wv = tid >> 6, ln = lane & 15, q = lane >> 4;
    int row0 = (blockIdx.x * 4 + wv) * 32;
    f32x4 acc[2] = {};
#pragma unroll
    for (int ks = 0; ks < 8; ++ks) {
        bf16x8 a0 = *(const bf16x8*)&A[(size_t)(row0 + ln) * 256 + ks * 32 + q * 8];
        bf16x8 a1 = *(const bf16x8*)&A[(size_t)(row0 + 16 + ln) * 256 + ks * 32 + q * 8];
        size_t wi = (size_t)ln * 256 + ks * 32 + q * 8;
        bf16x8 bh = *(const bf16x8*)&wT[wi];
        acc[0] = mfma16(a0, bh, acc[0]);
        acc[1] = mfma16(a1, bh, acc[1]);
    }
    if (ln < 12) {
        float bv = bias[ln];
#pragma unroll
        for (int mt = 0; mt < 2; ++mt)
#pragma unroll
            for (int r = 0; r < 4; ++r)
                out[(size_t)(row0 + mt * 16 + q * 4 + r) * 12 + ln] = acc[mt][r] + bv;
    }
}

// ---------------------------------------------------------------------------
// Workspace (peak 50,708,480 B = 48.4 MB):
//   [0,        2473984)  split weights
//   [2473984,  4571136)  idxb
//   [4571136,  8765440)  x1 f32      (dead after head1; h2 bf16 overlays)
//   [8765440, 17154048)  x2 f32      (dead after head1)
//   [17154048,33931264)  Uf f32 (<=8MB) @ +0, Vb bf16 (<=4MB) @ +8MB;
//                        h1 bf16 (16MB) overlays whole region after edge3
//   [33931264,50708480)  x3 bf16
// ---------------------------------------------------------------------------
extern "C" void kernel_launch(void* const* d_in, const int* in_sizes, int n_in,
                              void* d_out, int out_size, void* d_ws, size_t ws_size,
                              hipStream_t stream)
{
    (void)in_sizes; (void)n_in; (void)out_size; (void)ws_size;
    const float* x   = (const float*)d_in[0];
    const float* pos = (const float*)d_in[1];
    const float* w1a = (const float*)d_in[2];  const float* b1a = (const float*)d_in[3];
    const float* w1b = (const float*)d_in[4];  const float* b1b = (const float*)d_in[5];
    const float* w2a = (const float*)d_in[6];  const float* b2a = (const float*)d_in[7];
    const float* w2b = (const float*)d_in[8];  const float* b2b = (const float*)d_in[9];
    const float* w3a = (const float*)d_in[10]; const float* b3a = (const float*)d_in[11];
    const float* w3b = (const float*)d_in[12]; const float* b3b = (const float*)d_in[13];
    const float* wf1 = (const float*)d_in[14]; const float* bf1 = (const float*)d_in[15];
    const float* wf2 = (const float*)d_in[16]; const float* bf2 = (const float*)d_in[17];
    const float* wf3 = (const float*)d_in[18]; const float* bf3 = (const float*)d_in[19];

    char* ws = (char*)d_ws;
    u16* t1uv = (u16*)(ws + 0);
    u16* t2uv = (u16*)(ws + 16384);
    u16* t3uv = (u16*)(ws + 49152);
    u16* t1b  = (u16*)(ws + 180224);
    u16* t2b  = (u16*)(ws + 196608);
    u16* t3b  = (u16*)(ws + 229376);
    u16* tf1  = (u16*)(ws + 491520);
    u16* tf2  = (u16*)(ws + 1933312);
    u16* tf3  = (u16*)(ws + 2457600);
    int*   idxb = (int*)(ws + 2473984);
    float* x1 = (float*)(ws + 4571136);
    float* x2 = (float*)(ws + 8765440);
    float* Uf = (float*)(ws + 17154048);           // <= 8 MB (edge3)
    u16*   Vb = (u16*)(ws + 17154048 + 8388608);   // <= 4 MB (edge3)
    u16*   x3 = (u16*)(ws + 33931264);
    u16*   h1 = (u16*)(ws + 17154048);    // overlays Uf/Vb after edge3
    u16*   h2 = (u16*)(ws + 4571136);     // overlays x1/x2 after head1

    prep_weights<<<2416, 256, 0, stream>>>(w1a, w1b, w2a, w2b, w3a, w3b, wf1, wf2, wf3,
                                           t1uv, t2uv, t3uv, t1b, t2b, t3b, tf1, tf2, tf3);
    knn_kernel<<<4096, 256, 0, stream>>>(pos, idxb);
    uv_gemm<  3, 32, 128><<<512, 256, 0, stream>>>(x,  t1uv, b1a, Uf, Vb);
    edge_pool< 64,  64, false, 2, 1><<<8192, 256, 0, stream>>>(Uf, Vb, idxb, t1b, b1b, x1);
    uv_gemm< 64, 64, 128><<<512, 256, 0, stream>>>(x1, t2uv, b2a, Uf, Vb);
    edge_pool< 64, 128, false, 2, 2><<<8192, 256, 0, stream>>>(Uf, Vb, idxb, t2b, b2b, x2);
    uv_gemm<128, 128, 256><<<512, 256, 0, stream>>>(x2, t3uv, b3a, Uf, Vb);
    edge_pool<128, 512, true, 2, 2><<<8192, 256, 0, stream>>>(Uf, Vb, idxb, t3b, b3b, x3);
    head1<<<512, 256, 0, stream>>>(x1, x2, x3, tf1, bf1, h1);
    head_bf<512, 256><<<512, 256, 0, stream>>>(h1, tf2, bf2, h2);
    head_gemm3<<<128, 256, 0, stream>>>(h2, tf3, bf3, (float*)d_out);
}